// Round 1
// baseline (684.850 us; speedup 1.0000x reference)
//
#include <hip/hip_runtime.h>

#define NB 2
#define CCH 256
#define LL 4096
#define NGRP 16
#define CPG 16
#define NHD 4
#define CHD 64
#define QR 768   // 3*C rows of qkv

// workspace layout in floats:
// [0,32)   group means   (n*16+g)
// [32,64)  group rstd
// [64,576)  a_c per (n,c)   : 2*256
// [576,1088) b_c per (n,c)  : 2*256
// [1088, 1088+2*768*4096)  qkv
// then 2*256*4096 attn out
#define OFF_A    64
#define OFF_B    576
#define OFF_QKV  1088
#define OFF_ATT  (1088 + NB*QR*LL)

// ---------------- kernel 1: group-norm statistics ----------------
__global__ __launch_bounds__(256)
void k_gnstats(const float* __restrict__ x, float* __restrict__ ws) {
    const int b = blockIdx.x;  // n*16+g ; group data is contiguous: 16 ch * 4096
    const float4* p = (const float4*)(x + (size_t)b * (CPG * LL));
    float s1 = 0.f, s2 = 0.f;
    for (int i = threadIdx.x; i < (CPG * LL) / 4; i += 256) {
        float4 v = p[i];
        s1 += (v.x + v.y) + (v.z + v.w);
        s2 += (v.x * v.x + v.y * v.y) + (v.z * v.z + v.w * v.w);
    }
    #pragma unroll
    for (int off = 32; off; off >>= 1) {
        s1 += __shfl_down(s1, off);
        s2 += __shfl_down(s2, off);
    }
    __shared__ float r1[4], r2[4];
    const int wid = threadIdx.x >> 6;
    if ((threadIdx.x & 63) == 0) { r1[wid] = s1; r2[wid] = s2; }
    __syncthreads();
    if (threadIdx.x == 0) {
        s1 = r1[0] + r1[1] + r1[2] + r1[3];
        s2 = r2[0] + r2[1] + r2[2] + r2[3];
        const float inv = 1.f / (float)(CPG * LL);
        float m = s1 * inv;
        float var = s2 * inv - m * m;
        ws[b] = m;
        ws[32 + b] = rsqrtf(var + 1e-6f);
    }
}

// ---------------- kernel 2: per-channel affine coefficients ----------------
__global__ void k_prep(const float* __restrict__ gn_scale,
                       const float* __restrict__ gn_bias,
                       float* __restrict__ ws) {
    const int n = blockIdx.x;
    const int c = threadIdx.x;
    const int g = c >> 4;
    const float mu = ws[n * NGRP + g];
    const float rs = ws[32 + n * NGRP + g];
    const float a = rs * gn_scale[c];
    ws[OFF_A + n * CCH + c] = a;
    ws[OFF_B + n * CCH + c] = gn_bias[c] - mu * a;
}

// ---------------- kernel 3: QKV projection GEMM ----------------
// qkv[n][o][l] = sum_c w_qkv[o][c] * (a_c*x[c][l]+b_c) + b_qkv[o]
__global__ __launch_bounds__(256)
void k_qkv(const float* __restrict__ x, const float* __restrict__ w_qkv,
           const float* __restrict__ b_qkv, const float* __restrict__ ws,
           float* __restrict__ qkv) {
    const int l0 = blockIdx.x * 64;
    const int o0 = blockIdx.y * 64;
    const int n  = blockIdx.z;
    const float* Bx  = x + (size_t)n * CCH * LL;
    const float* ach = ws + OFF_A + n * CCH;
    const float* bch = ws + OFF_B + n * CCH;

    __shared__ float As[16][68];
    __shared__ float Bs[16][64];

    const int tid = threadIdx.x;
    const int ro = (tid >> 4) << 2;
    const int rl = (tid & 15) << 2;
    float acc[4][4] = {};

    for (int c0 = 0; c0 < CCH; c0 += 16) {
        {
            const int r   = tid >> 2;
            const int c4  = (tid & 3) << 2;
            float4 w = *(const float4*)(w_qkv + (size_t)(o0 + r) * CCH + c0 + c4);
            As[c4 + 0][r] = w.x; As[c4 + 1][r] = w.y;
            As[c4 + 2][r] = w.z; As[c4 + 3][r] = w.w;
            const int rr  = tid >> 4;
            const int lc4 = (tid & 15) << 2;
            const float a = ach[c0 + rr], bb = bch[c0 + rr];
            float4 xv = *(const float4*)(Bx + (size_t)(c0 + rr) * LL + l0 + lc4);
            float4 bv;
            bv.x = a * xv.x + bb; bv.y = a * xv.y + bb;
            bv.z = a * xv.z + bb; bv.w = a * xv.w + bb;
            *(float4*)&Bs[rr][lc4] = bv;
        }
        __syncthreads();
        #pragma unroll
        for (int kk = 0; kk < 16; kk++) {
            float4 a4 = *(const float4*)&As[kk][ro];
            float4 b4 = *(const float4*)&Bs[kk][rl];
            const float av[4] = {a4.x, a4.y, a4.z, a4.w};
            const float bv[4] = {b4.x, b4.y, b4.z, b4.w};
            #pragma unroll
            for (int i = 0; i < 4; i++)
                #pragma unroll
                for (int j = 0; j < 4; j++)
                    acc[i][j] = fmaf(av[i], bv[j], acc[i][j]);
        }
        __syncthreads();
    }
    float* outp = qkv + ((size_t)n * QR + o0) * LL + l0;
    #pragma unroll
    for (int i = 0; i < 4; i++) {
        const float b = b_qkv[o0 + ro + i];
        float4 v;
        v.x = acc[i][0] + b; v.y = acc[i][1] + b;
        v.z = acc[i][2] + b; v.w = acc[i][3] + b;
        *(float4*)(outp + (size_t)(ro + i) * LL + rl) = v;
    }
}

// ---------------- kernel 4: flash attention ----------------
// swizzle: rotate 16B blocks within a 64-float row by 4*(row>>2); all accesses
// are aligned float4 blocks -> <=2-way bank conflicts for every pattern used.
__device__ __forceinline__ int swz(int r, int c4) {
    return (r << 6) + ((c4 + ((r >> 2) << 2)) & 63);
}

__global__ __launch_bounds__(256, 2)
void k_attn(const float* __restrict__ qkv, float* __restrict__ attn_out) {
    const int t0 = blockIdx.x * 64;
    const int h  = blockIdx.y;
    const int n  = blockIdx.z;
    const float* qb = qkv + ((size_t)n * QR + h * CHD) * LL;
    const float* kb = qb + (size_t)CCH * LL;
    const float* vb = qb + (size_t)2 * CCH * LL;

    __shared__ __align__(16) float qs[64 * 64];
    __shared__ __align__(16) float ks[64 * 64];
    __shared__ __align__(16) float vs[64 * 64];
    __shared__ __align__(16) float ps[64 * 64];

    const int tid = threadIdx.x;
    const int lr  = tid >> 4;          // 0..15
    const int lc4 = (tid & 15) << 2;   // 0..60

    #pragma unroll
    for (int i = 0; i < 4; i++) {
        const int r = lr + (i << 4);
        *(float4*)&qs[swz(r, lc4)] = *(const float4*)(qb + (size_t)r * LL + t0 + lc4);
    }

    const int tt = (tid >> 4) << 2;    // this thread's 4 query rows
    const int ss = (tid & 15) << 2;    // this thread's 4 key cols (score phase)
    const int cc = (tid & 15) << 2;    // this thread's 4 channel rows (PV phase)

    float m[4], lsum[4] = {0.f, 0.f, 0.f, 0.f};
    float oacc[4][4] = {};
    #pragma unroll
    for (int i = 0; i < 4; i++) m[i] = -1e30f;

    for (int s0 = 0; s0 < LL; s0 += 64) {
        __syncthreads();   // previous iteration done with ks/vs/ps
        #pragma unroll
        for (int i = 0; i < 4; i++) {
            const int r = lr + (i << 4);
            *(float4*)&ks[swz(r, lc4)] = *(const float4*)(kb + (size_t)r * LL + s0 + lc4);
            *(float4*)&vs[swz(r, lc4)] = *(const float4*)(vb + (size_t)r * LL + s0 + lc4);
        }
        __syncthreads();

        // scores: sc[i][j] = q[:,tt+i] . k[:,ss+j]
        float sc[4][4] = {};
        #pragma unroll 8
        for (int c = 0; c < 64; c++) {
            float4 q4 = *(const float4*)&qs[swz(c, tt)];
            float4 k4 = *(const float4*)&ks[swz(c, ss)];
            const float qv[4] = {q4.x, q4.y, q4.z, q4.w};
            const float kv[4] = {k4.x, k4.y, k4.z, k4.w};
            #pragma unroll
            for (int i = 0; i < 4; i++)
                #pragma unroll
                for (int j = 0; j < 4; j++)
                    sc[i][j] = fmaf(qv[i], kv[j], sc[i][j]);
        }
        #pragma unroll
        for (int i = 0; i < 4; i++)
            #pragma unroll
            for (int j = 0; j < 4; j++)
                sc[i][j] *= 0.125f;   // scale^2 = 1/sqrt(64)

        // online softmax (state replicated across each 16-lane group)
        float alpha[4];
        #pragma unroll
        for (int i = 0; i < 4; i++) {
            float mx = fmaxf(fmaxf(sc[i][0], sc[i][1]), fmaxf(sc[i][2], sc[i][3]));
            mx = fmaxf(mx, __shfl_xor(mx, 1));
            mx = fmaxf(mx, __shfl_xor(mx, 2));
            mx = fmaxf(mx, __shfl_xor(mx, 4));
            mx = fmaxf(mx, __shfl_xor(mx, 8));
            const float mn = fmaxf(m[i], mx);
            alpha[i] = __expf(m[i] - mn);
            m[i] = mn;
            float rs = 0.f;
            #pragma unroll
            for (int j = 0; j < 4; j++) {
                const float p = __expf(sc[i][j] - mn);
                sc[i][j] = p;
                rs += p;
            }
            rs += __shfl_xor(rs, 1);
            rs += __shfl_xor(rs, 2);
            rs += __shfl_xor(rs, 4);
            rs += __shfl_xor(rs, 8);
            lsum[i] = lsum[i] * alpha[i] + rs;
        }
        #pragma unroll
        for (int i = 0; i < 4; i++) {
            float4 pv;
            pv.x = sc[i][0]; pv.y = sc[i][1]; pv.z = sc[i][2]; pv.w = sc[i][3];
            *(float4*)&ps[swz(tt + i, ss)] = pv;
        }
        #pragma unroll
        for (int ci = 0; ci < 4; ci++)
            #pragma unroll
            for (int tj = 0; tj < 4; tj++)
                oacc[ci][tj] *= alpha[tj];
        __syncthreads();

        // PV: oacc[ci][tj] += sum_s v[cc+ci][s] * p[tt+tj][s]
        #pragma unroll 4
        for (int s = 0; s < 64; s += 4) {
            float4 vv[4], pp[4];
            #pragma unroll
            for (int i = 0; i < 4; i++) vv[i] = *(const float4*)&vs[swz(cc + i, s)];
            #pragma unroll
            for (int j = 0; j < 4; j++) pp[j] = *(const float4*)&ps[swz(tt + j, s)];
            #pragma unroll
            for (int i = 0; i < 4; i++)
                #pragma unroll
                for (int j = 0; j < 4; j++) {
                    oacc[i][j] = fmaf(vv[i].x, pp[j].x, oacc[i][j]);
                    oacc[i][j] = fmaf(vv[i].y, pp[j].y, oacc[i][j]);
                    oacc[i][j] = fmaf(vv[i].z, pp[j].z, oacc[i][j]);
                    oacc[i][j] = fmaf(vv[i].w, pp[j].w, oacc[i][j]);
                }
        }
    }

    float inv[4];
    #pragma unroll
    for (int j = 0; j < 4; j++) inv[j] = 1.0f / lsum[j];
    float* ob = attn_out + ((size_t)n * CCH + h * CHD) * LL + t0;
    #pragma unroll
    for (int i = 0; i < 4; i++) {
        float4 v;
        v.x = oacc[i][0] * inv[0]; v.y = oacc[i][1] * inv[1];
        v.z = oacc[i][2] * inv[2]; v.w = oacc[i][3] * inv[3];
        *(float4*)(ob + (size_t)(cc + i) * LL + tt) = v;
    }
}

// ---------------- kernel 5: out projection + residual ----------------
__global__ __launch_bounds__(256)
void k_out(const float* __restrict__ attn, const float* __restrict__ w_out,
           const float* __restrict__ b_out, const float* __restrict__ x,
           float* __restrict__ out) {
    const int l0 = blockIdx.x * 64;
    const int o0 = blockIdx.y * 64;
    const int n  = blockIdx.z;
    const float* Bm = attn + (size_t)n * CCH * LL;

    __shared__ float As[16][68];
    __shared__ float Bs[16][64];

    const int tid = threadIdx.x;
    const int ro = (tid >> 4) << 2;
    const int rl = (tid & 15) << 2;
    float acc[4][4] = {};

    for (int c0 = 0; c0 < CCH; c0 += 16) {
        {
            const int r  = tid >> 2;
            const int c4 = (tid & 3) << 2;
            float4 w = *(const float4*)(w_out + (size_t)(o0 + r) * CCH + c0 + c4);
            As[c4 + 0][r] = w.x; As[c4 + 1][r] = w.y;
            As[c4 + 2][r] = w.z; As[c4 + 3][r] = w.w;
            const int rr  = tid >> 4;
            const int lc4 = (tid & 15) << 2;
            *(float4*)&Bs[rr][lc4] = *(const float4*)(Bm + (size_t)(c0 + rr) * LL + l0 + lc4);
        }
        __syncthreads();
        #pragma unroll
        for (int kk = 0; kk < 16; kk++) {
            float4 a4 = *(const float4*)&As[kk][ro];
            float4 b4 = *(const float4*)&Bs[kk][rl];
            const float av[4] = {a4.x, a4.y, a4.z, a4.w};
            const float bv[4] = {b4.x, b4.y, b4.z, b4.w};
            #pragma unroll
            for (int i = 0; i < 4; i++)
                #pragma unroll
                for (int j = 0; j < 4; j++)
                    acc[i][j] = fmaf(av[i], bv[j], acc[i][j]);
        }
        __syncthreads();
    }
    const float* xb = x + ((size_t)n * CCH + o0) * LL + l0;
    float* ob = out + ((size_t)n * CCH + o0) * LL + l0;
    #pragma unroll
    for (int i = 0; i < 4; i++) {
        const float b = b_out[o0 + ro + i];
        float4 xv = *(const float4*)(xb + (size_t)(ro + i) * LL + rl);
        float4 v;
        v.x = acc[i][0] + b + xv.x; v.y = acc[i][1] + b + xv.y;
        v.z = acc[i][2] + b + xv.z; v.w = acc[i][3] + b + xv.w;
        *(float4*)(ob + (size_t)(ro + i) * LL + rl) = v;
    }
}

extern "C" void kernel_launch(void* const* d_in, const int* in_sizes, int n_in,
                              void* d_out, int out_size, void* d_ws, size_t ws_size,
                              hipStream_t stream) {
    (void)in_sizes; (void)n_in; (void)out_size; (void)ws_size;
    const float* x        = (const float*)d_in[0];
    const float* gn_scale = (const float*)d_in[1];
    const float* gn_bias  = (const float*)d_in[2];
    const float* w_qkv    = (const float*)d_in[3];
    const float* b_qkv    = (const float*)d_in[4];
    const float* w_out    = (const float*)d_in[5];
    const float* b_out    = (const float*)d_in[6];
    float* out = (float*)d_out;
    float* ws  = (float*)d_ws;
    float* qkv = ws + OFF_QKV;
    float* att = ws + OFF_ATT;

    k_gnstats<<<dim3(NB * NGRP), 256, 0, stream>>>(x, ws);
    k_prep<<<dim3(NB), 256, 0, stream>>>(gn_scale, gn_bias, ws);
    k_qkv<<<dim3(LL / 64, QR / 64, NB), 256, 0, stream>>>(x, w_qkv, b_qkv, ws, qkv);
    k_attn<<<dim3(LL / 64, NHD, NB), 256, 0, stream>>>(qkv, att);
    k_out<<<dim3(LL / 64, CCH / 64, NB), 256, 0, stream>>>(att, w_out, b_out, x, out);
}

// Round 2
// 311.324 us; speedup vs baseline: 2.1998x; 2.1998x over previous
//
#include <hip/hip_runtime.h>

#define NB 2
#define CCH 256
#define LL 4096
#define NGRP 16
#define CPG 16
#define NHD 4
#define CHD 64
#define QR 768   // 3*C rows of qkv

typedef __attribute__((ext_vector_type(8))) short short8;   // 8 x bf16 (4 VGPR)
typedef __attribute__((ext_vector_type(4))) float f32x4;    // MFMA acc

// workspace layout in FLOAT units:
// [0,32) group means | [32,64) group rstd | [64,576) a_c | [576,1088) b_c
// qT bf16 [n][h][t=4096][c=64]  -> 1048576 floats
// kT bf16 same                  -> 1048576
// v  bf16 [n][h][c=64][s=4096]  -> 1048576
// att f32 [n][256][4096]        -> 2097152
#define OFF_A    64
#define OFF_B    576
#define OFF_QT   1088
#define QT_F     (NB*NHD*LL*CHD/2)
#define OFF_KT   (OFF_QT + QT_F)
#define OFF_V    (OFF_KT + QT_F)
#define OFF_ATT  (OFF_V + QT_F)

__device__ __forceinline__ unsigned short f2bf(float f) {
    unsigned int u = __builtin_bit_cast(unsigned int, f);
    u += 0x7fffu + ((u >> 16) & 1u);   // round-to-nearest-even
    return (unsigned short)(u >> 16);
}

// ---------------- kernel 1: group-norm statistics ----------------
__global__ __launch_bounds__(256)
void k_gnstats(const float* __restrict__ x, float* __restrict__ ws) {
    const int b = blockIdx.x;  // n*16+g ; group data contiguous: 16 ch * 4096
    const float4* p = (const float4*)(x + (size_t)b * (CPG * LL));
    float s1 = 0.f, s2 = 0.f;
    for (int i = threadIdx.x; i < (CPG * LL) / 4; i += 256) {
        float4 v = p[i];
        s1 += (v.x + v.y) + (v.z + v.w);
        s2 += (v.x * v.x + v.y * v.y) + (v.z * v.z + v.w * v.w);
    }
    #pragma unroll
    for (int off = 32; off; off >>= 1) {
        s1 += __shfl_down(s1, off);
        s2 += __shfl_down(s2, off);
    }
    __shared__ float r1[4], r2[4];
    const int wid = threadIdx.x >> 6;
    if ((threadIdx.x & 63) == 0) { r1[wid] = s1; r2[wid] = s2; }
    __syncthreads();
    if (threadIdx.x == 0) {
        s1 = r1[0] + r1[1] + r1[2] + r1[3];
        s2 = r2[0] + r2[1] + r2[2] + r2[3];
        const float inv = 1.f / (float)(CPG * LL);
        float m = s1 * inv;
        float var = s2 * inv - m * m;
        ws[b] = m;
        ws[32 + b] = rsqrtf(var + 1e-6f);
    }
}

// ---------------- kernel 2: per-channel affine coefficients ----------------
__global__ void k_prep(const float* __restrict__ gn_scale,
                       const float* __restrict__ gn_bias,
                       float* __restrict__ ws) {
    const int n = blockIdx.x;
    const int c = threadIdx.x;
    const int g = c >> 4;
    const float mu = ws[n * NGRP + g];
    const float rs = ws[32 + n * NGRP + g];
    const float a = rs * gn_scale[c];
    ws[OFF_A + n * CCH + c] = a;
    ws[OFF_B + n * CCH + c] = gn_bias[c] - mu * a;
}

// ---------------- kernel 3: QKV projection GEMM (fp32 VALU) ----------------
// qkv[o][l] = sum_c w_qkv[o][c]*(a_c*x[c][l]+b_c) + b_qkv[o]
// epilogue: Q,K written TRANSPOSED bf16 [n][h][t][c]; V written bf16 [n][h][c][s]
__global__ __launch_bounds__(256)
void k_qkv(const float* __restrict__ x, const float* __restrict__ w_qkv,
           const float* __restrict__ b_qkv, const float* __restrict__ ws,
           unsigned short* __restrict__ qT, unsigned short* __restrict__ kT,
           unsigned short* __restrict__ vv) {
    const int l0 = blockIdx.x * 64;
    const int o0 = blockIdx.y * 64;   // one head's worth of one of Q/K/V
    const int n  = blockIdx.z;
    const float* Bx  = x + (size_t)n * CCH * LL;
    const float* ach = ws + OFF_A + n * CCH;
    const float* bch = ws + OFF_B + n * CCH;

    __shared__ float As[16][68];
    __shared__ float Bs[16][64];

    const int tid = threadIdx.x;
    const int ro = (tid >> 4) << 2;
    const int rl = (tid & 15) << 2;
    float acc[4][4] = {};

    for (int c0 = 0; c0 < CCH; c0 += 16) {
        {
            const int r   = tid >> 2;
            const int c4  = (tid & 3) << 2;
            float4 w = *(const float4*)(w_qkv + (size_t)(o0 + r) * CCH + c0 + c4);
            As[c4 + 0][r] = w.x; As[c4 + 1][r] = w.y;
            As[c4 + 2][r] = w.z; As[c4 + 3][r] = w.w;
            const int rr  = tid >> 4;
            const int lc4 = (tid & 15) << 2;
            const float a = ach[c0 + rr], bb = bch[c0 + rr];
            float4 xv = *(const float4*)(Bx + (size_t)(c0 + rr) * LL + l0 + lc4);
            float4 bv;
            bv.x = a * xv.x + bb; bv.y = a * xv.y + bb;
            bv.z = a * xv.z + bb; bv.w = a * xv.w + bb;
            *(float4*)&Bs[rr][lc4] = bv;
        }
        __syncthreads();
        #pragma unroll
        for (int kk = 0; kk < 16; kk++) {
            float4 a4 = *(const float4*)&As[kk][ro];
            float4 b4 = *(const float4*)&Bs[kk][rl];
            const float av[4] = {a4.x, a4.y, a4.z, a4.w};
            const float bv[4] = {b4.x, b4.y, b4.z, b4.w};
            #pragma unroll
            for (int i = 0; i < 4; i++)
                #pragma unroll
                for (int j = 0; j < 4; j++)
                    acc[i][j] = fmaf(av[i], bv[j], acc[i][j]);
        }
        __syncthreads();
    }

    const int h = (o0 >> 6) & 3;
    float b4v[4];
    #pragma unroll
    for (int i = 0; i < 4; i++) b4v[i] = b_qkv[o0 + ro + i];

    if (o0 >= 512) {
        // V: [n][h][c][s] bf16, straight
        unsigned short* vb = vv + ((size_t)n * NHD + h) * CHD * LL;
        #pragma unroll
        for (int i = 0; i < 4; i++) {
            ushort4 u;
            u.x = f2bf(acc[i][0] + b4v[i]); u.y = f2bf(acc[i][1] + b4v[i]);
            u.z = f2bf(acc[i][2] + b4v[i]); u.w = f2bf(acc[i][3] + b4v[i]);
            *(ushort4*)(vb + (size_t)(ro + i) * LL + l0 + rl) = u;
        }
    } else {
        // Q or K: transposed [n][h][t][c] bf16
        unsigned short* tb = (o0 < 256 ? qT : kT) + ((size_t)n * NHD + h) * LL * CHD;
        #pragma unroll
        for (int j = 0; j < 4; j++) {
            ushort4 u;
            u.x = f2bf(acc[0][j] + b4v[0]); u.y = f2bf(acc[1][j] + b4v[1]);
            u.z = f2bf(acc[2][j] + b4v[2]); u.w = f2bf(acc[3][j] + b4v[3]);
            *(ushort4*)(tb + (size_t)(l0 + rl + j) * CHD + ro) = u;
        }
    }
}

// ---------------- kernel 4: MFMA flash attention ----------------
// Per wave: 16 queries (t = tw + (lane&15)). Computes S^T = K^T Q via
// mfma(A=kT rows, B=qT rows): D col = t (lane-local!), rows = s.
// Softmax along s is in-register (16 vals) + shfl_xor(16,32).
// PV: O = V * P^T via mfma(A=v rows, B=Ps rows); P bounced through a
// per-wave LDS slice with XOR swizzle (t&7)<<4 to kill 128B-row conflicts.
__global__ __launch_bounds__(256, 2)
void k_attn(const unsigned short* __restrict__ qT,
            const unsigned short* __restrict__ kT,
            const unsigned short* __restrict__ vv,
            float* __restrict__ att) {
    const int t0 = blockIdx.x * 64;
    const int h  = blockIdx.y;
    const int n  = blockIdx.z;
    const int tid = threadIdx.x;
    const int w   = tid >> 6;
    const int l   = tid & 63;
    const int r16 = l & 15;
    const int g   = l >> 4;

    const size_t nh = (size_t)n * NHD + h;
    const unsigned short* qb = qT + nh * LL * CHD;
    const unsigned short* kb = kT + nh * LL * CHD;
    const unsigned short* vb = vv + nh * CHD * LL;

    __shared__ __align__(16) unsigned short ps[4][16 * 64];  // per-wave 2KB

    const int tw = t0 + w * 16;
    const int swz = (r16 & 7) << 4;
    char* prow = (char*)&ps[w][0] + r16 * 128;

    // Q B-fragments (held in registers for the whole kernel)
    short8 qf0 = *(const short8*)(qb + (size_t)(tw + r16) * CHD + g * 8);
    short8 qf1 = *(const short8*)(qb + (size_t)(tw + r16) * CHD + 32 + g * 8);

    f32x4 oacc[4];
    #pragma unroll
    for (int cb = 0; cb < 4; cb++) oacc[cb] = (f32x4){0.f, 0.f, 0.f, 0.f};
    float mrow = -1e30f, lsum = 0.f;
    const float kscale = 0.125f * 1.44269504f;  // 1/sqrt(64) * log2(e)

    for (int s0 = 0; s0 < LL; s0 += 64) {
        // ---- issue all global loads up front (K then V) ----
        short8 kf0[4], kf1[4], vf0[4], vf1[4];
        #pragma unroll
        for (int sb = 0; sb < 4; sb++) {
            const unsigned short* kr = kb + (size_t)(s0 + sb * 16 + r16) * CHD + g * 8;
            kf0[sb] = *(const short8*)(kr);
            kf1[sb] = *(const short8*)(kr + 32);
        }
        #pragma unroll
        for (int cb = 0; cb < 4; cb++) {
            const unsigned short* vr = vb + (size_t)(cb * 16 + r16) * LL + s0 + g * 8;
            vf0[cb] = *(const short8*)(vr);
            vf1[cb] = *(const short8*)(vr + 32);
        }

        // ---- S^T = K^T Q ----
        f32x4 sacc[4];
        #pragma unroll
        for (int sb = 0; sb < 4; sb++) {
            f32x4 z = (f32x4){0.f, 0.f, 0.f, 0.f};
            z = __builtin_amdgcn_mfma_f32_16x16x32_bf16(kf0[sb], qf0, z, 0, 0, 0);
            z = __builtin_amdgcn_mfma_f32_16x16x32_bf16(kf1[sb], qf1, z, 0, 0, 0);
            sacc[sb] = z;
        }

        // ---- online softmax (exp2 domain), lane-local along s ----
        float pv[4][4];
        float mx = -1e30f;
        #pragma unroll
        for (int sb = 0; sb < 4; sb++)
            #pragma unroll
            for (int r = 0; r < 4; r++) {
                float v = sacc[sb][r] * kscale;
                pv[sb][r] = v;
                mx = fmaxf(mx, v);
            }
        mx = fmaxf(mx, __shfl_xor(mx, 16));
        mx = fmaxf(mx, __shfl_xor(mx, 32));
        const float mnew = fmaxf(mrow, mx);
        const float alpha = exp2f(mrow - mnew);
        mrow = mnew;
        float rs = 0.f;
        #pragma unroll
        for (int sb = 0; sb < 4; sb++)
            #pragma unroll
            for (int r = 0; r < 4; r++) {
                float p = exp2f(pv[sb][r] - mnew);
                pv[sb][r] = p;
                rs += p;
            }
        rs += __shfl_xor(rs, 16);
        rs += __shfl_xor(rs, 32);
        lsum = lsum * alpha + rs;

        // ---- pack P to bf16, write P[t][s] rows to swizzled LDS ----
        #pragma unroll
        for (int sb = 0; sb < 4; sb++) {
            unsigned int lo = (unsigned int)f2bf(pv[sb][0]) | ((unsigned int)f2bf(pv[sb][1]) << 16);
            unsigned int hi = (unsigned int)f2bf(pv[sb][2]) | ((unsigned int)f2bf(pv[sb][3]) << 16);
            *(uint2*)(prow + ((sb * 32 + g * 8) ^ swz)) = make_uint2(lo, hi);
        }

        // ---- rescale O ----
        #pragma unroll
        for (int cb = 0; cb < 4; cb++)
            #pragma unroll
            for (int r = 0; r < 4; r++) oacc[cb][r] *= alpha;

        // ---- read P B-fragments back ----
        short8 pf0 = *(const short8*)(prow + ((g * 16) ^ swz));
        short8 pf1 = *(const short8*)(prow + ((64 + g * 16) ^ swz));

        // ---- O += V P^T ----
        #pragma unroll
        for (int cb = 0; cb < 4; cb++) {
            oacc[cb] = __builtin_amdgcn_mfma_f32_16x16x32_bf16(vf0[cb], pf0, oacc[cb], 0, 0, 0);
            oacc[cb] = __builtin_amdgcn_mfma_f32_16x16x32_bf16(vf1[cb], pf1, oacc[cb], 0, 0, 0);
        }
    }

    const float inv = 1.f / lsum;   // lane-local: one t per lane
    float* ob = att + ((size_t)n * CCH + h * CHD) * LL + tw + r16;
    #pragma unroll
    for (int cb = 0; cb < 4; cb++)
        #pragma unroll
        for (int r = 0; r < 4; r++)
            ob[(size_t)(cb * 16 + g * 4 + r) * LL] = oacc[cb][r] * inv;
}

// ---------------- kernel 5: out projection + residual ----------------
__global__ __launch_bounds__(256)
void k_out(const float* __restrict__ attn, const float* __restrict__ w_out,
           const float* __restrict__ b_out, const float* __restrict__ x,
           float* __restrict__ out) {
    const int l0 = blockIdx.x * 64;
    const int o0 = blockIdx.y * 64;
    const int n  = blockIdx.z;
    const float* Bm = attn + (size_t)n * CCH * LL;

    __shared__ float As[16][68];
    __shared__ float Bs[16][64];

    const int tid = threadIdx.x;
    const int ro = (tid >> 4) << 2;
    const int rl = (tid & 15) << 2;
    float acc[4][4] = {};

    for (int c0 = 0; c0 < CCH; c0 += 16) {
        {
            const int r  = tid >> 2;
            const int c4 = (tid & 3) << 2;
            float4 w = *(const float4*)(w_out + (size_t)(o0 + r) * CCH + c0 + c4);
            As[c4 + 0][r] = w.x; As[c4 + 1][r] = w.y;
            As[c4 + 2][r] = w.z; As[c4 + 3][r] = w.w;
            const int rr  = tid >> 4;
            const int lc4 = (tid & 15) << 2;
            *(float4*)&Bs[rr][lc4] = *(const float4*)(Bm + (size_t)(c0 + rr) * LL + l0 + lc4);
        }
        __syncthreads();
        #pragma unroll
        for (int kk = 0; kk < 16; kk++) {
            float4 a4 = *(const float4*)&As[kk][ro];
            float4 b4 = *(const float4*)&Bs[kk][rl];
            const float av[4] = {a4.x, a4.y, a4.z, a4.w};
            const float bv[4] = {b4.x, b4.y, b4.z, b4.w};
            #pragma unroll
            for (int i = 0; i < 4; i++)
                #pragma unroll
                for (int j = 0; j < 4; j++)
                    acc[i][j] = fmaf(av[i], bv[j], acc[i][j]);
        }
        __syncthreads();
    }
    const float* xb = x + ((size_t)n * CCH + o0) * LL + l0;
    float* ob = out + ((size_t)n * CCH + o0) * LL + l0;
    #pragma unroll
    for (int i = 0; i < 4; i++) {
        const float b = b_out[o0 + ro + i];
        float4 xv = *(const float4*)(xb + (size_t)(ro + i) * LL + rl);
        float4 v;
        v.x = acc[i][0] + b + xv.x; v.y = acc[i][1] + b + xv.y;
        v.z = acc[i][2] + b + xv.z; v.w = acc[i][3] + b + xv.w;
        *(float4*)(ob + (size_t)(ro + i) * LL + rl) = v;
    }
}

extern "C" void kernel_launch(void* const* d_in, const int* in_sizes, int n_in,
                              void* d_out, int out_size, void* d_ws, size_t ws_size,
                              hipStream_t stream) {
    (void)in_sizes; (void)n_in; (void)out_size; (void)ws_size;
    const float* x        = (const float*)d_in[0];
    const float* gn_scale = (const float*)d_in[1];
    const float* gn_bias  = (const float*)d_in[2];
    const float* w_qkv    = (const float*)d_in[3];
    const float* b_qkv    = (const float*)d_in[4];
    const float* w_out    = (const float*)d_in[5];
    const float* b_out    = (const float*)d_in[6];
    float* out = (float*)d_out;
    float* ws  = (float*)d_ws;
    unsigned short* qT = (unsigned short*)(ws + OFF_QT);
    unsigned short* kT = (unsigned short*)(ws + OFF_KT);
    unsigned short* vv = (unsigned short*)(ws + OFF_V);
    float* att = ws + OFF_ATT;

    k_gnstats<<<dim3(NB * NGRP), 256, 0, stream>>>(x, ws);
    k_prep<<<dim3(NB), 256, 0, stream>>>(gn_scale, gn_bias, ws);
    k_qkv<<<dim3(LL / 64, QR / 64, NB), 256, 0, stream>>>(x, w_qkv, b_qkv, ws, qT, kT, vv);
    k_attn<<<dim3(LL / 64, NHD, NB), 256, 0, stream>>>(qT, kT, vv, att);
    k_out<<<dim3(LL / 64, CCH / 64, NB), 256, 0, stream>>>(att, w_out, b_out, x, out);
}